// Round 1
// baseline (4427.661 us; speedup 1.0000x reference)
//
#include <hip/hip_runtime.h>
#include <cmath>

#define B_   64
#define T_   256
#define D_   1024
#define DIN_ 1074
#define H_   256

// ---------------------------------------------------------------------------
// PRE[mv][n] = bias_dir[row] + sum_{k<50} mask_embed[mv][k] * W_ih_dir[row][1024+k]
// n in [0,2048): n<1024 -> forward rows, n>=1024 -> backward rows
// ---------------------------------------------------------------------------
__global__ __launch_bounds__(256) void k_pre(
    const float* __restrict__ me, const float* __restrict__ Wf,
    const float* __restrict__ Wb, const float* __restrict__ bf,
    const float* __restrict__ bb, float* __restrict__ PRE) {
  int idx = blockIdx.x * 256 + threadIdx.x;   // 4096 total
  if (idx >= 4096) return;
  int mv = idx >> 11, n = idx & 2047;
  int dir = n >> 10, row = n & 1023;
  const float* W    = dir ? Wb : Wf;
  const float* bias = dir ? bb : bf;
  const float* wrow = W + (size_t)row * DIN_ + 1024;
  const float* m    = me + mv * 50;
  float s = bias[row];
  #pragma unroll 10
  for (int k = 0; k < 50; ++k) s += m[k] * wrow[k];
  PRE[idx] = s;
}

// ---------------------------------------------------------------------------
// Wp[dir][k4][row] = float4{ W_hh_dir[row][4k4 .. 4k4+3] }   (k-major pack)
// ---------------------------------------------------------------------------
__global__ __launch_bounds__(256) void k_wp(
    const float* __restrict__ Whf, const float* __restrict__ Whb,
    float4* __restrict__ Wp) {
  int idx = blockIdx.x * 256 + threadIdx.x;   // 2*64*1024 = 131072
  int dir = idx >> 16, rem = idx & 65535;
  int k4 = rem >> 10, row = rem & 1023;
  const float* W = dir ? Whb : Whf;
  Wp[idx] = *(const float4*)(W + (size_t)row * H_ + k4 * 4);
}

// ---------------------------------------------------------------------------
// XW[(b*T+t)][n] = sents[b,t,:1024] . W_ih_dir[row][:1024] + PRE[mask[b,t]][n]
// M=16384, N=2048, K=1024.  128x128 tile, BK=16, 256 thr, 8x8 microtile.
// ---------------------------------------------------------------------------
#define BM 128
#define BN 128
#define BK 16
__global__ __launch_bounds__(256) void k_gemm(
    const float* __restrict__ A, const float* __restrict__ Wf,
    const float* __restrict__ Wb, const float* __restrict__ PRE,
    const int* __restrict__ masks, float* __restrict__ XW) {
  __shared__ __align__(16) float As[BK][BM + 4];
  __shared__ __align__(16) float Bs[BK][BN + 4];
  int tid = threadIdx.x;
  int m0 = blockIdx.y * BM, n0 = blockIdx.x * BN;
  int tm = tid >> 4, tn = tid & 15;
  float acc[8][8];
  #pragma unroll
  for (int i = 0; i < 8; ++i)
    #pragma unroll
    for (int j = 0; j < 8; ++j) acc[i][j] = 0.f;

  int arow = tid >> 2, acol = (tid & 3) * 4;   // A: 64 rows/pass x 16 k
  int brow = tid >> 1, bcol = (tid & 1) * 8;   // B: 128 rows x 8 k halves
  int ng = n0 + brow;                           // uniform f/b per tile (1024%128==0)
  const float* bsrc = (ng < 1024) ? (Wf + (size_t)ng * DIN_)
                                  : (Wb + (size_t)(ng - 1024) * DIN_);
  for (int k0 = 0; k0 < 1024; k0 += BK) {
    #pragma unroll
    for (int p = 0; p < 2; ++p) {
      float4 a4 = *(const float4*)(A + (size_t)(m0 + arow + p * 64) * 1024 + k0 + acol);
      As[acol + 0][arow + p * 64] = a4.x;
      As[acol + 1][arow + p * 64] = a4.y;
      As[acol + 2][arow + p * 64] = a4.z;
      As[acol + 3][arow + p * 64] = a4.w;
    }
    {
      // W rows have stride 1074 floats -> only 8B-aligned; use float2 loads
      const float* s = bsrc + k0 + bcol;
      float2 b0 = *(const float2*)(s);
      float2 b1 = *(const float2*)(s + 2);
      float2 b2 = *(const float2*)(s + 4);
      float2 b3 = *(const float2*)(s + 6);
      Bs[bcol + 0][brow] = b0.x; Bs[bcol + 1][brow] = b0.y;
      Bs[bcol + 2][brow] = b1.x; Bs[bcol + 3][brow] = b1.y;
      Bs[bcol + 4][brow] = b2.x; Bs[bcol + 5][brow] = b2.y;
      Bs[bcol + 6][brow] = b3.x; Bs[bcol + 7][brow] = b3.y;
    }
    __syncthreads();
    #pragma unroll
    for (int kk = 0; kk < BK; ++kk) {
      float a[8], bv[8];
      #pragma unroll
      for (int i = 0; i < 8; ++i) a[i]  = As[kk][tm * 8 + i];
      #pragma unroll
      for (int j = 0; j < 8; ++j) bv[j] = Bs[kk][tn * 8 + j];
      #pragma unroll
      for (int i = 0; i < 8; ++i)
        #pragma unroll
        for (int j = 0; j < 8; ++j) acc[i][j] += a[i] * bv[j];
    }
    __syncthreads();
  }
  #pragma unroll
  for (int i = 0; i < 8; ++i) {
    int m = m0 + tm * 8 + i;
    int mv = masks[m];
    const float* pr = PRE + mv * 2048 + n0 + tn * 8;
    float* o = XW + (size_t)m * 2048 + n0 + tn * 8;
    #pragma unroll
    for (int j = 0; j < 8; ++j) o[j] = acc[i][j] + pr[j];
  }
}

// ---------------------------------------------------------------------------
// Persistent per-(batch,dir) LSTM. 128 WGs x 256 thr. Thread c owns column c:
// gate rows c, 256+c, 512+c, 768+c. c-state in register, h via 1KB LDS.
// Backward dir reads XW row (len-1-s) and writes ctx row (len-1-s): identical.
// ---------------------------------------------------------------------------
__global__ __launch_bounds__(256) void k_lstm(
    const float* __restrict__ XW, const float4* __restrict__ Wp,
    const int* __restrict__ lens, float* __restrict__ ctx) {
  int bx = blockIdx.x;
  int dir = bx & 1, b = bx >> 1;
  int c = threadIdx.x;
  int len = lens[b];
  const float4* W = Wp + (size_t)dir * 65536;
  __shared__ __align__(16) float hs[H_];
  hs[c] = 0.f;
  float cc = 0.f;
  const float* xwb = XW + (size_t)b * T_ * 2048 + dir * 1024;
  float* cb = ctx + (size_t)b * T_ * 512 + dir * 256;
  __syncthreads();
  for (int s = 0; s < len; ++s) {
    float ai = 0.f, af = 0.f, ag = 0.f, ao = 0.f;
    #pragma unroll 8
    for (int k4 = 0; k4 < 64; ++k4) {
      float4 h4 = *(const float4*)(hs + k4 * 4);       // LDS broadcast
      float4 wi = W[k4 * 1024 + c];
      float4 wf = W[k4 * 1024 + 256 + c];
      float4 wg = W[k4 * 1024 + 512 + c];
      float4 wo = W[k4 * 1024 + 768 + c];
      ai += h4.x * wi.x + h4.y * wi.y + h4.z * wi.z + h4.w * wi.w;
      af += h4.x * wf.x + h4.y * wf.y + h4.z * wf.z + h4.w * wf.w;
      ag += h4.x * wg.x + h4.y * wg.y + h4.z * wg.z + h4.w * wg.w;
      ao += h4.x * wo.x + h4.y * wo.y + h4.z * wo.z + h4.w * wo.w;
    }
    int tx = dir ? (len - 1 - s) : s;
    const float* g = xwb + (size_t)tx * 2048;
    float gi = g[c] + ai;
    float gf = g[256 + c] + af;
    float gg = g[512 + c] + ag;
    float go = g[768 + c] + ao;
    float si = 1.f / (1.f + expf(-gi));
    float sf = 1.f / (1.f + expf(-gf));
    float so = 1.f / (1.f + expf(-go));
    float cn = sf * cc + si * tanhf(gg);
    float hn = so * tanhf(cn);
    cc = cn;
    cb[(size_t)tx * 512 + c] = hn;
    __syncthreads();        // all reads of old hs done
    hs[c] = hn;
    __syncthreads();        // new hs visible
  }
  for (int s = len; s < T_; ++s) cb[(size_t)s * 512 + c] = 0.f;
}

// ---------------------------------------------------------------------------
// Per-b: avg over masked t, then tri[b][t][0..1] = (ctx+avg).W_tri^T + b_tri
// ---------------------------------------------------------------------------
__global__ __launch_bounds__(256) void k_avgtri(
    const float* __restrict__ ctx, const int* __restrict__ masks,
    const float* __restrict__ Wtri, const float* __restrict__ btri,
    float* __restrict__ tri) {
  int b = blockIdx.x, tid = threadIdx.x;
  __shared__ float av[512];
  __shared__ float wt[1024];
  wt[tid] = Wtri[tid];           wt[tid + 256] = Wtri[tid + 256];
  wt[tid + 512] = Wtri[tid + 512]; wt[tid + 768] = Wtri[tid + 768];
  const float* cb = ctx + (size_t)b * T_ * 512;
  float s0 = 0.f, s1 = 0.f, msum = 0.f;
  for (int t = 0; t < T_; ++t) {
    int m = masks[b * T_ + t];
    if (m) {
      float mf = (float)m;
      s0 += mf * cb[(size_t)t * 512 + tid];
      s1 += mf * cb[(size_t)t * 512 + 256 + tid];
      msum += mf;
    }
  }
  av[tid] = s0 / msum;
  av[256 + tid] = s1 / msum;
  __syncthreads();
  int wave = tid >> 6, lane = tid & 63;
  float bt0 = btri[0], bt1 = btri[1];
  for (int t = wave; t < T_; t += 4) {     // one wave per t
    const float* cr = cb + (size_t)t * 512;
    float p0 = 0.f, p1 = 0.f;
    #pragma unroll
    for (int q = 0; q < 8; ++q) {
      int h = lane + q * 64;
      float x = cr[h] + av[h];
      p0 += x * wt[h];
      p1 += x * wt[512 + h];
    }
    #pragma unroll
    for (int off = 32; off > 0; off >>= 1) {
      p0 += __shfl_down(p0, off);
      p1 += __shfl_down(p1, off);
    }
    if (lane == 0) {
      tri[((size_t)b * T_ + t) * 2 + 0] = p0 + bt0;
      tri[((size_t)b * T_ + t) * 2 + 1] = p1 + bt1;
    }
  }
}

// ---------------------------------------------------------------------------
// CRF forward/backward, 2 states. One wave, thread b owns chain b.
// ---------------------------------------------------------------------------
__device__ __forceinline__ float lse2(float a, float b) {
  float m = fmaxf(a, b);
  return m + logf(expf(a - m) + expf(b - m));
}

__global__ __launch_bounds__(64) void k_crf(
    const float* __restrict__ tri, const int* __restrict__ lens,
    const float* __restrict__ trans, float* __restrict__ alph,
    float* __restrict__ sel, float* __restrict__ snb) {
  int b = threadIdx.x;
  if (b >= 64) return;
  const float* f = tri + (size_t)b * T_ * 2;
  float* aw = alph + (size_t)b * T_ * 2;
  int L = lens[b];
  float t00 = trans[0], t01 = trans[1], t10 = trans[2], t11 = trans[3];
  float a0 = f[0], a1 = f[1];
  aw[0] = a0; aw[1] = a1;
  for (int t = 1; t < T_; ++t) {
    if (t < L) {
      float c0 = f[2 * t]     + lse2(a0 + t00, a1 + t01);
      float c1 = f[2 * t + 1] + lse2(a0 + t10, a1 + t11);
      a0 = c0; a1 = c1;
    }
    aw[2 * t] = a0; aw[2 * t + 1] = a1;
  }
  float logZ = lse2(aw[2 * (L - 1)], aw[2 * (L - 1) + 1]);
  float b0 = 0.f, b1 = 0.f, sn = 0.f;
  {
    float s = (T_ - 1 < L) ? expf(aw[2 * (T_ - 1) + 1] - logZ) : 0.f;
    sel[b * T_ + T_ - 1] = s; sn += s;
  }
  for (int t = T_ - 2; t >= 0; --t) {
    if (t < L - 1) {
      float e0 = b0 + f[2 * (t + 1)];
      float e1 = b1 + f[2 * (t + 1) + 1];
      float n0 = lse2(e0 + t00, e1 + t10);   // over source state i
      float n1 = lse2(e0 + t01, e1 + t11);
      b0 = n0; b1 = n1;
    } else { b0 = 0.f; b1 = 0.f; }
    float s = (t < L) ? expf(aw[2 * t + 1] + b1 - logZ) : 0.f;
    sel[b * T_ + t] = s; sn += s;
  }
  snb[b] = sn;
}

// ---------------------------------------------------------------------------
// Per-b: sent_v = sum_t sel*ctx ; scores = sent_v.W_lab^T + b_lab
// ---------------------------------------------------------------------------
__global__ __launch_bounds__(256) void k_sentv(
    const float* __restrict__ ctx, const float* __restrict__ sel,
    const float* __restrict__ Wlab, const float* __restrict__ blab,
    float* __restrict__ scores) {
  int b = blockIdx.x, tid = threadIdx.x;
  __shared__ float ss[T_];
  __shared__ float red[3][4];
  ss[tid] = sel[b * T_ + tid];
  __syncthreads();
  const float* cb = ctx + (size_t)b * T_ * 512;
  float sv0 = 0.f, sv1 = 0.f;
  for (int t = 0; t < T_; ++t) {
    float s = ss[t];
    if (s != 0.f) {                       // wave-uniform skip of masked tail
      sv0 += s * cb[(size_t)t * 512 + tid];
      sv1 += s * cb[(size_t)t * 512 + 256 + tid];
    }
  }
  int wave = tid >> 6, lane = tid & 63;
  #pragma unroll
  for (int k = 0; k < 3; ++k) {
    float p = sv0 * Wlab[k * 512 + tid] + sv1 * Wlab[k * 512 + 256 + tid];
    #pragma unroll
    for (int off = 32; off > 0; off >>= 1) p += __shfl_down(p, off);
    if (lane == 0) red[k][wave] = p;
  }
  __syncthreads();
  if (tid < 3) {
    float r = red[tid][0] + red[tid][1] + red[tid][2] + red[tid][3];
    scores[b * 3 + tid] = r + blab[tid];
  }
}

// ---------------------------------------------------------------------------
// Final scalars: cls_loss and norm_pen
// ---------------------------------------------------------------------------
__global__ __launch_bounds__(64) void k_final(
    const float* __restrict__ scores, const int* __restrict__ labels,
    const float* __restrict__ snb, const float* __restrict__ trans,
    float* __restrict__ out) {
  int b = threadIdx.x;
  float s0 = scores[b * 3], s1 = scores[b * 3 + 1], s2 = scores[b * 3 + 2];
  float m = fmaxf(s0, fmaxf(s1, s2));
  float lse = m + logf(expf(s0 - m) + expf(s1 - m) + expf(s2 - m));
  int lab = labels[b];
  float sl = lab == 0 ? s0 : (lab == 1 ? s1 : s2);
  float closs = lse - sl;                 // -log p[label]
  float sn = snb[b];
  #pragma unroll
  for (int off = 32; off > 0; off >>= 1) {
    closs += __shfl_down(closs, off);
    sn    += __shfl_down(sn, off);
  }
  if (b == 0) {
    float pena = fmaxf(trans[2] - trans[0], 0.f) + fmaxf(trans[1] - trans[3], 0.f);
    out[0] = closs / 64.f;
    out[1] = pena / 64.f + sn / 64.f;     // C1*pena/B + C2*mean(s_norm)
  }
}

// ---------------------------------------------------------------------------
extern "C" void kernel_launch(void* const* d_in, const int* in_sizes, int n_in,
                              void* d_out, int out_size, void* d_ws, size_t ws_size,
                              hipStream_t stream) {
  const float* sents  = (const float*)d_in[0];
  const int*   masks  = (const int*)d_in[1];
  const int*   lens   = (const int*)d_in[2];
  const int*   labels = (const int*)d_in[3];
  const float* me     = (const float*)d_in[4];
  const float* Wihf   = (const float*)d_in[5];
  const float* Whhf   = (const float*)d_in[6];
  const float* bf     = (const float*)d_in[7];
  const float* Wihb   = (const float*)d_in[8];
  const float* Whhb   = (const float*)d_in[9];
  const float* bb     = (const float*)d_in[10];
  const float* Wtri   = (const float*)d_in[11];
  const float* btri   = (const float*)d_in[12];
  const float* Wlab   = (const float*)d_in[13];
  const float* blab   = (const float*)d_in[14];
  const float* trans  = (const float*)d_in[15];
  float* out = (float*)d_out;

  // workspace layout (~170.3 MB total)
  float*  XW   = (float*)d_ws;                           // 16384*2048
  float*  CTX  = XW + (size_t)16384 * 2048;              // 64*256*512
  float4* WP   = (float4*)(CTX + (size_t)64 * 256 * 512);// 131072 float4
  float*  PRE  = (float*)(WP + 131072);                  // 4096
  float*  TRI  = PRE + 4096;                             // 32768
  float*  ALPH = TRI + 32768;                            // 32768
  float*  SEL  = ALPH + 32768;                           // 16384
  float*  SCOR = SEL + 16384;                            // 192
  float*  SNB  = SCOR + 192;                             // 64

  hipLaunchKernelGGL(k_pre,    dim3(16),      dim3(256), 0, stream, me, Wihf, Wihb, bf, bb, PRE);
  hipLaunchKernelGGL(k_wp,     dim3(512),     dim3(256), 0, stream, Whhf, Whhb, WP);
  hipLaunchKernelGGL(k_gemm,   dim3(16, 128), dim3(256), 0, stream, sents, Wihf, Wihb, PRE, masks, XW);
  hipLaunchKernelGGL(k_lstm,   dim3(128),     dim3(256), 0, stream, XW, WP, lens, CTX);
  hipLaunchKernelGGL(k_avgtri, dim3(64),      dim3(256), 0, stream, CTX, masks, Wtri, btri, TRI);
  hipLaunchKernelGGL(k_crf,    dim3(1),       dim3(64),  0, stream, TRI, lens, trans, ALPH, SEL, SNB);
  hipLaunchKernelGGL(k_sentv,  dim3(64),      dim3(256), 0, stream, CTX, SEL, Wlab, blab, SCOR);
  hipLaunchKernelGGL(k_final,  dim3(1),       dim3(64),  0, stream, SCOR, labels, SNB, trans, out);
}

// Round 2
// 2998.456 us; speedup vs baseline: 1.4766x; 1.4766x over previous
//
#include <hip/hip_runtime.h>
#include <cmath>

#define B_   64
#define T_   256
#define D_   1024
#define DIN_ 1074
#define H_   256

typedef _Float16 h2_t __attribute__((ext_vector_type(2)));

// ---------------------------------------------------------------------------
// PRE[mv][n] = bias_dir[row] + sum_{k<50} mask_embed[mv][k] * W_ih_dir[row][1024+k]
// ---------------------------------------------------------------------------
__global__ __launch_bounds__(256) void k_pre(
    const float* __restrict__ me, const float* __restrict__ Wf,
    const float* __restrict__ Wb, const float* __restrict__ bf,
    const float* __restrict__ bb, float* __restrict__ PRE) {
  int idx = blockIdx.x * 256 + threadIdx.x;   // 4096 total
  if (idx >= 4096) return;
  int mv = idx >> 11, n = idx & 2047;
  int dir = n >> 10, row = n & 1023;
  const float* W    = dir ? Wb : Wf;
  const float* bias = dir ? bb : bf;
  const float* wrow = W + (size_t)row * DIN_ + 1024;
  const float* m    = me + mv * 50;
  float s = bias[row];
  #pragma unroll 10
  for (int k = 0; k < 50; ++k) s += m[k] * wrow[k];
  PRE[idx] = s;
}

// ---------------------------------------------------------------------------
// Pack W_hh (both dirs) to fp16, layout WH[dir][k8][gate][hc][8 halfs]
// row = gate*256+hc ; halfs e = k8*8+e  (k-contiguous per 16B chunk)
// ---------------------------------------------------------------------------
__global__ __launch_bounds__(256) void k_wph(
    const float* __restrict__ Whf, const float* __restrict__ Whb,
    _Float16* __restrict__ WH) {
  int idx = blockIdx.x * 256 + threadIdx.x;   // 65536 total
  int dir = idx >> 15, rem = idx & 32767;
  int k8 = rem >> 10, gate = (rem >> 8) & 3, hc = rem & 255;
  const float* W = dir ? Whb : Whf;
  const float* src = W + (size_t)(gate * 256 + hc) * H_ + k8 * 8;
  _Float16* dst = WH + ((size_t)(((dir * 32 + k8) * 4 + gate) * 256 + hc)) * 8;
  #pragma unroll
  for (int e = 0; e < 8; ++e) dst[e] = (_Float16)src[e];
}

// ---------------------------------------------------------------------------
// XW[(b*T+t)][n] = sents[b,t,:1024] . W_ih_dir[row][:1024] + PRE[mask[b,t]][n]
// fp32 GEMM, 128x128 tile, BK=16, 256 thr, 8x8 microtile.
// ---------------------------------------------------------------------------
#define BM 128
#define BN 128
#define BK 16
__global__ __launch_bounds__(256) void k_gemm(
    const float* __restrict__ A, const float* __restrict__ Wf,
    const float* __restrict__ Wb, const float* __restrict__ PRE,
    const int* __restrict__ masks, float* __restrict__ XW) {
  __shared__ __align__(16) float As[BK][BM + 4];
  __shared__ __align__(16) float Bs[BK][BN + 4];
  int tid = threadIdx.x;
  int m0 = blockIdx.y * BM, n0 = blockIdx.x * BN;
  int tm = tid >> 4, tn = tid & 15;
  float acc[8][8];
  #pragma unroll
  for (int i = 0; i < 8; ++i)
    #pragma unroll
    for (int j = 0; j < 8; ++j) acc[i][j] = 0.f;

  int arow = tid >> 2, acol = (tid & 3) * 4;
  int brow = tid >> 1, bcol = (tid & 1) * 8;
  int ng = n0 + brow;
  const float* bsrc = (ng < 1024) ? (Wf + (size_t)ng * DIN_)
                                  : (Wb + (size_t)(ng - 1024) * DIN_);
  for (int k0 = 0; k0 < 1024; k0 += BK) {
    #pragma unroll
    for (int p = 0; p < 2; ++p) {
      float4 a4 = *(const float4*)(A + (size_t)(m0 + arow + p * 64) * 1024 + k0 + acol);
      As[acol + 0][arow + p * 64] = a4.x;
      As[acol + 1][arow + p * 64] = a4.y;
      As[acol + 2][arow + p * 64] = a4.z;
      As[acol + 3][arow + p * 64] = a4.w;
    }
    {
      const float* s = bsrc + k0 + bcol;
      float2 b0 = *(const float2*)(s);
      float2 b1 = *(const float2*)(s + 2);
      float2 b2 = *(const float2*)(s + 4);
      float2 b3 = *(const float2*)(s + 6);
      Bs[bcol + 0][brow] = b0.x; Bs[bcol + 1][brow] = b0.y;
      Bs[bcol + 2][brow] = b1.x; Bs[bcol + 3][brow] = b1.y;
      Bs[bcol + 4][brow] = b2.x; Bs[bcol + 5][brow] = b2.y;
      Bs[bcol + 6][brow] = b3.x; Bs[bcol + 7][brow] = b3.y;
    }
    __syncthreads();
    #pragma unroll
    for (int kk = 0; kk < BK; ++kk) {
      float a[8], bv[8];
      #pragma unroll
      for (int i = 0; i < 8; ++i) a[i]  = As[kk][tm * 8 + i];
      #pragma unroll
      for (int j = 0; j < 8; ++j) bv[j] = Bs[kk][tn * 8 + j];
      #pragma unroll
      for (int i = 0; i < 8; ++i)
        #pragma unroll
        for (int j = 0; j < 8; ++j) acc[i][j] += a[i] * bv[j];
    }
    __syncthreads();
  }
  #pragma unroll
  for (int i = 0; i < 8; ++i) {
    int m = m0 + tm * 8 + i;
    int mv = masks[m];
    const float* pr = PRE + mv * 2048 + n0 + tn * 8;
    float* o = XW + (size_t)m * 2048 + n0 + tn * 8;
    #pragma unroll
    for (int j = 0; j < 8; ++j) o[j] = acc[i][j] + pr[j];
  }
}

// ---------------------------------------------------------------------------
// Batched persistent LSTM: 32 WGs = 16 groups(4 batches) x 2 dirs, 1024 thr.
// Compute phase: thread (gate=tid>>8, hc=tid&255) owns one W row (fp16,
// register-reused across the 4 batches, accumulated via v_dot2_f32_f16).
// Update phase: thread (j=tid>>8, hc=tid&255) owns (batch j, hidden hc):
// reads 4 gates from LDS, fp32 c-state in register, writes h to ctx (fp32)
// and to LDS as fp16 half2[k2][j] for the next step's dot products.
// ---------------------------------------------------------------------------
__global__ __launch_bounds__(1024) void k_lstm(
    const float* __restrict__ XW, const _Float16* __restrict__ WH,
    const int* __restrict__ lens, float* __restrict__ ctx) {
  int bx = blockIdx.x;
  int dir = bx & 1, grp = bx >> 1;
  int tid = threadIdx.x;
  int hc = tid & 255, hi = tid >> 8;    // hi = gate (compute) / batch j (update)

  __shared__ __align__(16) _Float16 hsT[1024];   // half2 hs2[k2=128][j=4]
  __shared__ __align__(16) float gacc[4][256][4]; // [gate][hc][j]

  int b0 = grp * 4;
  int myb = b0 + hi;
  int mylen = lens[myb];
  int lmax = max(max(lens[b0], lens[b0 + 1]), max(lens[b0 + 2], lens[b0 + 3]));

  hsT[tid] = (_Float16)0.f;
  float cstate = 0.f;

  const uint4* Wbase = (const uint4*)WH + (size_t)dir * 32768 + hi * 256 + hc;
  const uint4* hp = (const uint4*)hsT;
  const float* xwb = XW + (size_t)myb * T_ * 2048 + dir * 1024;
  float* cbase = ctx + (size_t)myb * T_ * 512 + dir * 256;
  __syncthreads();

  for (int s = 0; s < lmax; ++s) {
    // ---- compute phase: acc[j] = W_row(gate=hi, col hc) . h[:,j]
    float acc0 = 0.f, acc1 = 0.f, acc2 = 0.f, acc3 = 0.f;
    #pragma unroll 8
    for (int k8 = 0; k8 < 32; ++k8) {
      uint4 wv = Wbase[k8 * 1024];
      const unsigned int* wq = &wv.x;
      #pragma unroll
      for (int q = 0; q < 4; ++q) {
        uint4 hv = hp[k8 * 4 + q];         // LDS broadcast: 4 batches @ k2
        h2_t w2 = __builtin_bit_cast(h2_t, wq[q]);
        acc0 = __builtin_amdgcn_fdot2(w2, __builtin_bit_cast(h2_t, hv.x), acc0, false);
        acc1 = __builtin_amdgcn_fdot2(w2, __builtin_bit_cast(h2_t, hv.y), acc1, false);
        acc2 = __builtin_amdgcn_fdot2(w2, __builtin_bit_cast(h2_t, hv.z), acc2, false);
        acc3 = __builtin_amdgcn_fdot2(w2, __builtin_bit_cast(h2_t, hv.w), acc3, false);
      }
    }
    *(float4*)&gacc[hi][hc][0] = make_float4(acc0, acc1, acc2, acc3);
    __syncthreads();

    // ---- update phase: batch j=hi, hidden hc
    if (s < mylen) {
      int tx = dir ? (mylen - 1 - s) : s;
      const float* g = xwb + (size_t)tx * 2048;
      float gi = g[hc]        + gacc[0][hc][hi];
      float gf = g[256 + hc]  + gacc[1][hc][hi];
      float gg = g[512 + hc]  + gacc[2][hc][hi];
      float go = g[768 + hc]  + gacc[3][hc][hi];
      float si = 1.f / (1.f + expf(-gi));
      float sf = 1.f / (1.f + expf(-gf));
      float so = 1.f / (1.f + expf(-go));
      float cn = sf * cstate + si * tanhf(gg);
      float hn = so * tanhf(cn);
      cstate = cn;
      cbase[(size_t)tx * 512 + hc] = hn;
      hsT[(hc >> 1) * 8 + hi * 2 + (hc & 1)] = (_Float16)hn;
    }
    __syncthreads();
  }
  // tail zero-fill for t >= len
  for (int t = mylen; t < T_; ++t) cbase[(size_t)t * 512 + hc] = 0.f;
}

// ---------------------------------------------------------------------------
// Per-b: avg over masked t, then tri[b][t][0..1] = (ctx+avg).W_tri^T + b_tri
// ---------------------------------------------------------------------------
__global__ __launch_bounds__(256) void k_avgtri(
    const float* __restrict__ ctx, const int* __restrict__ masks,
    const float* __restrict__ Wtri, const float* __restrict__ btri,
    float* __restrict__ tri) {
  int b = blockIdx.x, tid = threadIdx.x;
  __shared__ float av[512];
  __shared__ float wt[1024];
  wt[tid] = Wtri[tid];             wt[tid + 256] = Wtri[tid + 256];
  wt[tid + 512] = Wtri[tid + 512]; wt[tid + 768] = Wtri[tid + 768];
  const float* cb = ctx + (size_t)b * T_ * 512;
  float s0 = 0.f, s1 = 0.f, msum = 0.f;
  for (int t = 0; t < T_; ++t) {
    int m = masks[b * T_ + t];
    if (m) {
      float mf = (float)m;
      s0 += mf * cb[(size_t)t * 512 + tid];
      s1 += mf * cb[(size_t)t * 512 + 256 + tid];
      msum += mf;
    }
  }
  av[tid] = s0 / msum;
  av[256 + tid] = s1 / msum;
  __syncthreads();
  int wave = tid >> 6, lane = tid & 63;
  float bt0 = btri[0], bt1 = btri[1];
  for (int t = wave; t < T_; t += 4) {
    const float* cr = cb + (size_t)t * 512;
    float p0 = 0.f, p1 = 0.f;
    #pragma unroll
    for (int q = 0; q < 8; ++q) {
      int h = lane + q * 64;
      float x = cr[h] + av[h];
      p0 += x * wt[h];
      p1 += x * wt[512 + h];
    }
    #pragma unroll
    for (int off = 32; off > 0; off >>= 1) {
      p0 += __shfl_down(p0, off);
      p1 += __shfl_down(p1, off);
    }
    if (lane == 0) {
      tri[((size_t)b * T_ + t) * 2 + 0] = p0 + bt0;
      tri[((size_t)b * T_ + t) * 2 + 1] = p1 + bt1;
    }
  }
}

// ---------------------------------------------------------------------------
__device__ __forceinline__ float lse2(float a, float b) {
  float m = fmaxf(a, b);
  return m + logf(expf(a - m) + expf(b - m));
}

__global__ __launch_bounds__(64) void k_crf(
    const float* __restrict__ tri, const int* __restrict__ lens,
    const float* __restrict__ trans, float* __restrict__ alph,
    float* __restrict__ sel, float* __restrict__ snb) {
  int b = threadIdx.x;
  if (b >= 64) return;
  const float* f = tri + (size_t)b * T_ * 2;
  float* aw = alph + (size_t)b * T_ * 2;
  int L = lens[b];
  float t00 = trans[0], t01 = trans[1], t10 = trans[2], t11 = trans[3];
  float a0 = f[0], a1 = f[1];
  aw[0] = a0; aw[1] = a1;
  for (int t = 1; t < T_; ++t) {
    if (t < L) {
      float c0 = f[2 * t]     + lse2(a0 + t00, a1 + t01);
      float c1 = f[2 * t + 1] + lse2(a0 + t10, a1 + t11);
      a0 = c0; a1 = c1;
    }
    aw[2 * t] = a0; aw[2 * t + 1] = a1;
  }
  float logZ = lse2(aw[2 * (L - 1)], aw[2 * (L - 1) + 1]);
  float b0 = 0.f, b1 = 0.f, sn = 0.f;
  {
    float s = (T_ - 1 < L) ? expf(aw[2 * (T_ - 1) + 1] - logZ) : 0.f;
    sel[b * T_ + T_ - 1] = s; sn += s;
  }
  for (int t = T_ - 2; t >= 0; --t) {
    if (t < L - 1) {
      float e0 = b0 + f[2 * (t + 1)];
      float e1 = b1 + f[2 * (t + 1) + 1];
      float n0 = lse2(e0 + t00, e1 + t10);
      float n1 = lse2(e0 + t01, e1 + t11);
      b0 = n0; b1 = n1;
    } else { b0 = 0.f; b1 = 0.f; }
    float s = (t < L) ? expf(aw[2 * t + 1] + b1 - logZ) : 0.f;
    sel[b * T_ + t] = s; sn += s;
  }
  snb[b] = sn;
}

// ---------------------------------------------------------------------------
__global__ __launch_bounds__(256) void k_sentv(
    const float* __restrict__ ctx, const float* __restrict__ sel,
    const float* __restrict__ Wlab, const float* __restrict__ blab,
    float* __restrict__ scores) {
  int b = blockIdx.x, tid = threadIdx.x;
  __shared__ float ss[T_];
  __shared__ float red[3][4];
  ss[tid] = sel[b * T_ + tid];
  __syncthreads();
  const float* cb = ctx + (size_t)b * T_ * 512;
  float sv0 = 0.f, sv1 = 0.f;
  for (int t = 0; t < T_; ++t) {
    float s = ss[t];
    if (s != 0.f) {
      sv0 += s * cb[(size_t)t * 512 + tid];
      sv1 += s * cb[(size_t)t * 512 + 256 + tid];
    }
  }
  int wave = tid >> 6, lane = tid & 63;
  #pragma unroll
  for (int k = 0; k < 3; ++k) {
    float p = sv0 * Wlab[k * 512 + tid] + sv1 * Wlab[k * 512 + 256 + tid];
    #pragma unroll
    for (int off = 32; off > 0; off >>= 1) p += __shfl_down(p, off);
    if (lane == 0) red[k][wave] = p;
  }
  __syncthreads();
  if (tid < 3) {
    float r = red[tid][0] + red[tid][1] + red[tid][2] + red[tid][3];
    scores[b * 3 + tid] = r + blab[tid];
  }
}

// ---------------------------------------------------------------------------
__global__ __launch_bounds__(64) void k_final(
    const float* __restrict__ scores, const int* __restrict__ labels,
    const float* __restrict__ snb, const float* __restrict__ trans,
    float* __restrict__ out) {
  int b = threadIdx.x;
  float s0 = scores[b * 3], s1 = scores[b * 3 + 1], s2 = scores[b * 3 + 2];
  float m = fmaxf(s0, fmaxf(s1, s2));
  float lse = m + logf(expf(s0 - m) + expf(s1 - m) + expf(s2 - m));
  int lab = labels[b];
  float sl = lab == 0 ? s0 : (lab == 1 ? s1 : s2);
  float closs = lse - sl;
  float sn = snb[b];
  #pragma unroll
  for (int off = 32; off > 0; off >>= 1) {
    closs += __shfl_down(closs, off);
    sn    += __shfl_down(sn, off);
  }
  if (b == 0) {
    float pena = fmaxf(trans[2] - trans[0], 0.f) + fmaxf(trans[1] - trans[3], 0.f);
    out[0] = closs / 64.f;
    out[1] = pena / 64.f + sn / 64.f;
  }
}

// ---------------------------------------------------------------------------
extern "C" void kernel_launch(void* const* d_in, const int* in_sizes, int n_in,
                              void* d_out, int out_size, void* d_ws, size_t ws_size,
                              hipStream_t stream) {
  const float* sents  = (const float*)d_in[0];
  const int*   masks  = (const int*)d_in[1];
  const int*   lens   = (const int*)d_in[2];
  const int*   labels = (const int*)d_in[3];
  const float* me     = (const float*)d_in[4];
  const float* Wihf   = (const float*)d_in[5];
  const float* Whhf   = (const float*)d_in[6];
  const float* bf     = (const float*)d_in[7];
  const float* Wihb   = (const float*)d_in[8];
  const float* Whhb   = (const float*)d_in[9];
  const float* bb     = (const float*)d_in[10];
  const float* Wtri   = (const float*)d_in[11];
  const float* btri   = (const float*)d_in[12];
  const float* Wlab   = (const float*)d_in[13];
  const float* blab   = (const float*)d_in[14];
  const float* trans  = (const float*)d_in[15];
  float* out = (float*)d_out;

  float*     XW   = (float*)d_ws;                            // 16384*2048
  float*     CTX  = XW + (size_t)16384 * 2048;               // 64*256*512
  _Float16*  WH   = (_Float16*)(CTX + (size_t)64 * 256 * 512); // 524288 halfs (1MB)
  float*     PRE  = (float*)(WH + 524288);                   // 4096
  float*     TRI  = PRE + 4096;                              // 32768
  float*     ALPH = TRI + 32768;                             // 32768
  float*     SEL  = ALPH + 32768;                            // 16384
  float*     SCOR = SEL + 16384;                             // 192
  float*     SNB  = SCOR + 192;                              // 64

  hipLaunchKernelGGL(k_pre,    dim3(16),      dim3(256),  0, stream, me, Wihf, Wihb, bf, bb, PRE);
  hipLaunchKernelGGL(k_wph,    dim3(256),     dim3(256),  0, stream, Whhf, Whhb, WH);
  hipLaunchKernelGGL(k_gemm,   dim3(16, 128), dim3(256),  0, stream, sents, Wihf, Wihb, PRE, masks, XW);
  hipLaunchKernelGGL(k_lstm,   dim3(32),      dim3(1024), 0, stream, XW, WH, lens, CTX);
  hipLaunchKernelGGL(k_avgtri, dim3(64),      dim3(256),  0, stream, CTX, masks, Wtri, btri, TRI);
  hipLaunchKernelGGL(k_crf,    dim3(1),       dim3(64),   0, stream, TRI, lens, trans, ALPH, SEL, SNB);
  hipLaunchKernelGGL(k_sentv,  dim3(64),      dim3(256),  0, stream, CTX, SEL, Wlab, blab, SCOR);
  hipLaunchKernelGGL(k_final,  dim3(1),       dim3(64),   0, stream, SCOR, labels, SNB, trans, out);
}

// Round 3
// 2490.244 us; speedup vs baseline: 1.7780x; 1.2041x over previous
//
#include <hip/hip_runtime.h>
#include <cmath>

#define B_   64
#define T_   256
#define D_   1024
#define DIN_ 1074
#define H_   256

typedef _Float16 h2_t  __attribute__((ext_vector_type(2)));
typedef _Float16 f16x8 __attribute__((ext_vector_type(8)));
typedef float    f32x4 __attribute__((ext_vector_type(4)));

// ---------------------------------------------------------------------------
// PRE[mv][n] = bias_dir[row] + sum_{k<50} mask_embed[mv][k] * W_ih_dir[row][1024+k]
// ---------------------------------------------------------------------------
__global__ __launch_bounds__(256) void k_pre(
    const float* __restrict__ me, const float* __restrict__ Wf,
    const float* __restrict__ Wb, const float* __restrict__ bf,
    const float* __restrict__ bb, float* __restrict__ PRE) {
  int idx = blockIdx.x * 256 + threadIdx.x;   // 4096 total
  if (idx >= 4096) return;
  int mv = idx >> 11, n = idx & 2047;
  int dir = n >> 10, row = n & 1023;
  const float* W    = dir ? Wb : Wf;
  const float* bias = dir ? bb : bf;
  const float* wrow = W + (size_t)row * DIN_ + 1024;
  const float* m    = me + mv * 50;
  float s = bias[row];
  #pragma unroll 10
  for (int k = 0; k < 50; ++k) s += m[k] * wrow[k];
  PRE[idx] = s;
}

// ---------------------------------------------------------------------------
// Pack W_hh (both dirs) to fp16, layout WH[dir][k8][gate][hc][8 halfs]
// ---------------------------------------------------------------------------
__global__ __launch_bounds__(256) void k_wph(
    const float* __restrict__ Whf, const float* __restrict__ Whb,
    _Float16* __restrict__ WH) {
  int idx = blockIdx.x * 256 + threadIdx.x;   // 65536 total
  int dir = idx >> 15, rem = idx & 32767;
  int k8 = rem >> 10, gate = (rem >> 8) & 3, hc = rem & 255;
  const float* W = dir ? Whb : Whf;
  const float* src = W + (size_t)(gate * 256 + hc) * H_ + k8 * 8;
  _Float16* dst = WH + ((size_t)(((dir * 32 + k8) * 4 + gate) * 256 + hc)) * 8;
  #pragma unroll
  for (int e = 0; e < 8; ++e) dst[e] = (_Float16)src[e];
}

// ---------------------------------------------------------------------------
// Pack sents -> PA fp16 [16384][1024] and W_ih rows (cols 0..1023) -> PB fp16
// [2048][1024] (n<1024: forward rows, n>=1024: backward rows).
// ---------------------------------------------------------------------------
__global__ __launch_bounds__(256) void k_pack(
    const float* __restrict__ sents, const float* __restrict__ Wf,
    const float* __restrict__ Wb, _Float16* __restrict__ PA,
    _Float16* __restrict__ PB) {
  int i = blockIdx.x * 256 + threadIdx.x;     // 2359296 total
  if (i < 2097152) {
    size_t off = (size_t)i * 8;
    float4 a = *(const float4*)(sents + off);
    float4 b = *(const float4*)(sents + off + 4);
    _Float16 h[8] = {(_Float16)a.x, (_Float16)a.y, (_Float16)a.z, (_Float16)a.w,
                     (_Float16)b.x, (_Float16)b.y, (_Float16)b.z, (_Float16)b.w};
    *(uint4*)(PA + off) = *(const uint4*)h;
  } else {
    int j = i - 2097152;                      // 262144
    int n = j >> 7, k8 = j & 127;
    const float* src = (n < 1024) ? (Wf + (size_t)n * DIN_ + k8 * 8)
                                  : (Wb + (size_t)(n - 1024) * DIN_ + k8 * 8);
    float2 a0 = *(const float2*)(src);
    float2 a1 = *(const float2*)(src + 2);
    float2 a2 = *(const float2*)(src + 4);
    float2 a3 = *(const float2*)(src + 6);
    _Float16 h[8] = {(_Float16)a0.x, (_Float16)a0.y, (_Float16)a1.x, (_Float16)a1.y,
                     (_Float16)a2.x, (_Float16)a2.y, (_Float16)a3.x, (_Float16)a3.y};
    *(uint4*)(PB + (size_t)n * 1024 + k8 * 8) = *(const uint4*)h;
  }
}

// ---------------------------------------------------------------------------
// XW = PA @ PB^T + PRE[mask] : M=16384, N=2048, K=1024, fp16 MFMA 16x16x32.
// 128x128 tile, BK=32, 256 thr (4 waves, 2x2), 4x4 fragments/wave.
// ---------------------------------------------------------------------------
__global__ __launch_bounds__(256) void k_mm(
    const _Float16* __restrict__ PA, const _Float16* __restrict__ PB,
    const float* __restrict__ PRE, const int* __restrict__ masks,
    float* __restrict__ XW) {
  __shared__ __align__(16) _Float16 Al[128 * 32];
  __shared__ __align__(16) _Float16 Bl[128 * 32];
  int tid = threadIdx.x;
  int lane = tid & 63, wave = tid >> 6;
  int wr = wave >> 1, wc = wave & 1;
  int m0 = blockIdx.y * 128, n0 = blockIdx.x * 128;

  // staging: thread covers 16B of each tile per pass, 2 passes (rows +0/+64)
  int r0 = tid >> 2;                 // 0..63
  int kc = (tid & 3) * 8;            // 0,8,16,24
  const _Float16* asrc0 = PA + (size_t)(m0 + r0) * 1024 + kc;
  const _Float16* asrc1 = asrc0 + (size_t)64 * 1024;
  const _Float16* bsrc0 = PB + (size_t)(n0 + r0) * 1024 + kc;
  const _Float16* bsrc1 = bsrc0 + (size_t)64 * 1024;
  _Float16* adst0 = Al + r0 * 32 + kc;
  _Float16* adst1 = Al + (r0 + 64) * 32 + kc;
  _Float16* bdst0 = Bl + r0 * 32 + kc;
  _Float16* bdst1 = Bl + (r0 + 64) * 32 + kc;

  f32x4 acc[4][4];
  #pragma unroll
  for (int i = 0; i < 4; ++i)
    #pragma unroll
    for (int j = 0; j < 4; ++j)
      acc[i][j] = (f32x4){0.f, 0.f, 0.f, 0.f};

  int fr = lane & 15, fk = (lane >> 4) * 8;
  const _Float16* arow = Al + (wr * 64 + fr) * 32 + fk;
  const _Float16* brow = Bl + (wc * 64 + fr) * 32 + fk;

  for (int k0 = 0; k0 < 1024; k0 += 32) {
    uint4 a0 = *(const uint4*)(asrc0 + k0);
    uint4 a1 = *(const uint4*)(asrc1 + k0);
    uint4 b0 = *(const uint4*)(bsrc0 + k0);
    uint4 b1 = *(const uint4*)(bsrc1 + k0);
    __syncthreads();
    *(uint4*)adst0 = a0; *(uint4*)adst1 = a1;
    *(uint4*)bdst0 = b0; *(uint4*)bdst1 = b1;
    __syncthreads();
    f16x8 af[4], bf[4];
    #pragma unroll
    for (int fm = 0; fm < 4; ++fm) af[fm] = *(const f16x8*)(arow + fm * 16 * 32);
    #pragma unroll
    for (int fn = 0; fn < 4; ++fn) bf[fn] = *(const f16x8*)(brow + fn * 16 * 32);
    #pragma unroll
    for (int fm = 0; fm < 4; ++fm)
      #pragma unroll
      for (int fn = 0; fn < 4; ++fn)
        acc[fm][fn] = __builtin_amdgcn_mfma_f32_16x16x32_f16(af[fm], bf[fn], acc[fm][fn], 0, 0, 0);
  }

  // epilogue: D row=(lane>>4)*4+reg, col=lane&15
  int cr = (lane >> 4) * 4;
  #pragma unroll
  for (int fm = 0; fm < 4; ++fm) {
    #pragma unroll
    for (int r = 0; r < 4; ++r) {
      int m = m0 + wr * 64 + fm * 16 + cr + r;
      int mv = masks[m];
      const float* pr = PRE + mv * 2048;
      float* orow = XW + (size_t)m * 2048;
      #pragma unroll
      for (int fn = 0; fn < 4; ++fn) {
        int n = n0 + wc * 64 + fn * 16 + fr;
        orow[n] = acc[fm][fn][r] + pr[n];
      }
    }
  }
}

// ---------------------------------------------------------------------------
// Batched persistent LSTM, hybrid register/streamed W.
// 32 WGs = 16 groups(4 batches) x 2 dirs, 1024 thr.
// Thread (gate=tid>>8, hc=tid&255) owns one W row: k8 0..11 in VGPRs (48),
// k8 12..31 streamed per step. XW gate values prefetched at loop top.
// ---------------------------------------------------------------------------
#define NREG 12
__global__ __launch_bounds__(1024) void k_lstm(
    const float* __restrict__ XW, const _Float16* __restrict__ WH,
    const int* __restrict__ lens, float* __restrict__ ctx) {
  int bx = blockIdx.x;
  int dir = bx & 1, grp = bx >> 1;
  int tid = threadIdx.x;
  int hc = tid & 255, hi = tid >> 8;   // hi = gate (compute) / batch j (update)

  __shared__ __align__(16) _Float16 hsT[1024];     // [k2=128][j=4][2 halves]
  __shared__ __align__(16) float gacc[4 * 1024];   // [j][gate][hc]

  int b0 = grp * 4;
  int myb = b0 + hi;
  int mylen = lens[myb];
  int lmax = max(max(lens[b0], lens[b0 + 1]), max(lens[b0 + 2], lens[b0 + 3]));

  hsT[tid] = (_Float16)0.f;
  float cstate = 0.f;

  const uint4* Wb4 = (const uint4*)WH + (size_t)dir * 32768 + hi * 256 + hc;
  uint4 wreg[NREG];
  #pragma unroll
  for (int k8 = 0; k8 < NREG; ++k8) wreg[k8] = Wb4[k8 * 1024];

  const uint4* hp = (const uint4*)hsT;
  const float* xwb = XW + (size_t)myb * T_ * 2048 + dir * 1024;
  float* cbase = ctx + (size_t)myb * T_ * 512 + dir * 256;
  __syncthreads();

  for (int s = 0; s < lmax; ++s) {
    // prefetch this step's XW gate values (clamped addr; latency hides
    // under the register-dot phase)
    int sc = min(s, mylen - 1);
    int tx = dir ? (mylen - 1 - sc) : sc;
    const float* g = xwb + (size_t)tx * 2048;
    float g0 = g[hc], g1 = g[256 + hc], g2 = g[512 + hc], g3 = g[768 + hc];

    float acc0 = 0.f, acc1 = 0.f, acc2 = 0.f, acc3 = 0.f;
    // part 1: register-resident W
    #pragma unroll
    for (int k8 = 0; k8 < NREG; ++k8) {
      uint4 wv = wreg[k8];
      const unsigned int* wq = &wv.x;
      #pragma unroll
      for (int q = 0; q < 4; ++q) {
        uint4 hv = hp[k8 * 4 + q];
        h2_t w2 = __builtin_bit_cast(h2_t, wq[q]);
        acc0 = __builtin_amdgcn_fdot2(w2, __builtin_bit_cast(h2_t, hv.x), acc0, false);
        acc1 = __builtin_amdgcn_fdot2(w2, __builtin_bit_cast(h2_t, hv.y), acc1, false);
        acc2 = __builtin_amdgcn_fdot2(w2, __builtin_bit_cast(h2_t, hv.z), acc2, false);
        acc3 = __builtin_amdgcn_fdot2(w2, __builtin_bit_cast(h2_t, hv.w), acc3, false);
      }
    }
    // part 2: streamed W
    #pragma unroll 5
    for (int k8 = NREG; k8 < 32; ++k8) {
      uint4 wv = Wb4[k8 * 1024];
      const unsigned int* wq = &wv.x;
      #pragma unroll
      for (int q = 0; q < 4; ++q) {
        uint4 hv = hp[k8 * 4 + q];
        h2_t w2 = __builtin_bit_cast(h2_t, wq[q]);
        acc0 = __builtin_amdgcn_fdot2(w2, __builtin_bit_cast(h2_t, hv.x), acc0, false);
        acc1 = __builtin_amdgcn_fdot2(w2, __builtin_bit_cast(h2_t, hv.y), acc1, false);
        acc2 = __builtin_amdgcn_fdot2(w2, __builtin_bit_cast(h2_t, hv.z), acc2, false);
        acc3 = __builtin_amdgcn_fdot2(w2, __builtin_bit_cast(h2_t, hv.w), acc3, false);
      }
    }
    // [j][gate][hc] layout: consecutive-hc lanes -> conflict-free b32
    gacc[0 * 1024 + hi * 256 + hc] = acc0;
    gacc[1 * 1024 + hi * 256 + hc] = acc1;
    gacc[2 * 1024 + hi * 256 + hc] = acc2;
    gacc[3 * 1024 + hi * 256 + hc] = acc3;
    __syncthreads();

    if (s < mylen) {
      float gi = g0 + gacc[hi * 1024 + 0   + hc];
      float gf = g1 + gacc[hi * 1024 + 256 + hc];
      float gg = g2 + gacc[hi * 1024 + 512 + hc];
      float go = g3 + gacc[hi * 1024 + 768 + hc];
      float si = 1.f / (1.f + expf(-gi));
      float sf = 1.f / (1.f + expf(-gf));
      float so = 1.f / (1.f + expf(-go));
      float cn = sf * cstate + si * tanhf(gg);
      float hn = so * tanhf(cn);
      cstate = cn;
      cbase[(size_t)tx * 512 + hc] = hn;
      hsT[(hc >> 1) * 8 + hi * 2 + (hc & 1)] = (_Float16)hn;
    }
    __syncthreads();
  }
  for (int t = mylen; t < T_; ++t) cbase[(size_t)t * 512 + hc] = 0.f;
}

// ---------------------------------------------------------------------------
// Per-b: avg over masked t, then tri[b][t][0..1] = (ctx+avg).W_tri^T + b_tri
// ---------------------------------------------------------------------------
__global__ __launch_bounds__(256) void k_avgtri(
    const float* __restrict__ ctx, const int* __restrict__ masks,
    const float* __restrict__ Wtri, const float* __restrict__ btri,
    float* __restrict__ tri) {
  int b = blockIdx.x, tid = threadIdx.x;
  __shared__ float av[512];
  __shared__ float wt[1024];
  wt[tid] = Wtri[tid];             wt[tid + 256] = Wtri[tid + 256];
  wt[tid + 512] = Wtri[tid + 512]; wt[tid + 768] = Wtri[tid + 768];
  const float* cb = ctx + (size_t)b * T_ * 512;
  float s0 = 0.f, s1 = 0.f, msum = 0.f;
  for (int t = 0; t < T_; ++t) {
    int m = masks[b * T_ + t];
    if (m) {
      float mf = (float)m;
      s0 += mf * cb[(size_t)t * 512 + tid];
      s1 += mf * cb[(size_t)t * 512 + 256 + tid];
      msum += mf;
    }
  }
  av[tid] = s0 / msum;
  av[256 + tid] = s1 / msum;
  __syncthreads();
  int wave = tid >> 6, lane = tid & 63;
  float bt0 = btri[0], bt1 = btri[1];
  for (int t = wave; t < T_; t += 4) {
    const float* cr = cb + (size_t)t * 512;
    float p0 = 0.f, p1 = 0.f;
    #pragma unroll
    for (int q = 0; q < 8; ++q) {
      int h = lane + q * 64;
      float x = cr[h] + av[h];
      p0 += x * wt[h];
      p1 += x * wt[512 + h];
    }
    #pragma unroll
    for (int off = 32; off > 0; off >>= 1) {
      p0 += __shfl_down(p0, off);
      p1 += __shfl_down(p1, off);
    }
    if (lane == 0) {
      tri[((size_t)b * T_ + t) * 2 + 0] = p0 + bt0;
      tri[((size_t)b * T_ + t) * 2 + 1] = p1 + bt1;
    }
  }
}

// ---------------------------------------------------------------------------
__device__ __forceinline__ float lse2(float a, float b) {
  float m = fmaxf(a, b);
  return m + logf(expf(a - m) + expf(b - m));
}

__global__ __launch_bounds__(64) void k_crf(
    const float* __restrict__ tri, const int* __restrict__ lens,
    const float* __restrict__ trans, float* __restrict__ alph,
    float* __restrict__ sel, float* __restrict__ snb) {
  int b = threadIdx.x;
  if (b >= 64) return;
  const float* f = tri + (size_t)b * T_ * 2;
  float* aw = alph + (size_t)b * T_ * 2;
  int L = lens[b];
  float t00 = trans[0], t01 = trans[1], t10 = trans[2], t11 = trans[3];
  float a0 = f[0], a1 = f[1];
  aw[0] = a0; aw[1] = a1;
  for (int t = 1; t < T_; ++t) {
    if (t < L) {
      float c0 = f[2 * t]     + lse2(a0 + t00, a1 + t01);
      float c1 = f[2 * t + 1] + lse2(a0 + t10, a1 + t11);
      a0 = c0; a1 = c1;
    }
    aw[2 * t] = a0; aw[2 * t + 1] = a1;
  }
  float logZ = lse2(aw[2 * (L - 1)], aw[2 * (L - 1) + 1]);
  float b0 = 0.f, b1 = 0.f, sn = 0.f;
  {
    float s = (T_ - 1 < L) ? expf(aw[2 * (T_ - 1) + 1] - logZ) : 0.f;
    sel[b * T_ + T_ - 1] = s; sn += s;
  }
  for (int t = T_ - 2; t >= 0; --t) {
    if (t < L - 1) {
      float e0 = b0 + f[2 * (t + 1)];
      float e1 = b1 + f[2 * (t + 1) + 1];
      float n0 = lse2(e0 + t00, e1 + t10);
      float n1 = lse2(e0 + t01, e1 + t11);
      b0 = n0; b1 = n1;
    } else { b0 = 0.f; b1 = 0.f; }
    float s = (t < L) ? expf(aw[2 * t + 1] + b1 - logZ) : 0.f;
    sel[b * T_ + t] = s; sn += s;
  }
  snb[b] = sn;
}

// ---------------------------------------------------------------------------
__global__ __launch_bounds__(256) void k_sentv(
    const float* __restrict__ ctx, const float* __restrict__ sel,
    const float* __restrict__ Wlab, const float* __restrict__ blab,
    float* __restrict__ scores) {
  int b = blockIdx.x, tid = threadIdx.x;
  __shared__ float ss[T_];
  __shared__ float red[3][4];
  ss[tid] = sel[b * T_ + tid];
  __syncthreads();
  const float* cb = ctx + (size_t)b * T_ * 512;
  float sv0 = 0.f, sv1 = 0.f;
  for (int t = 0; t < T_; ++t) {
    float s = ss[t];
    if (s != 0.f) {
      sv0 += s * cb[(size_t)t * 512 + tid];
      sv1 += s * cb[(size_t)t * 512 + 256 + tid];
    }
  }
  int wave = tid >> 6, lane = tid & 63;
  #pragma unroll
  for (int k = 0; k < 3; ++k) {
    float p = sv0 * Wlab[k * 512 + tid] + sv1 * Wlab[k * 512 + 256 + tid];
    #pragma unroll
    for (int off = 32; off > 0; off >>= 1) p += __shfl_down(p, off);
    if (lane == 0) red[k][wave] = p;
  }
  __syncthreads();
  if (tid < 3) {
    float r = red[tid][0] + red[tid][1] + red[tid][2] + red[tid][3];
    scores[b * 3 + tid] = r + blab[tid];
  }
}

// ---------------------------------------------------------------------------
__global__ __launch_bounds__(64) void k_final(
    const float* __restrict__ scores, const int* __restrict__ labels,
    const float* __restrict__ snb, const float* __restrict__ trans,
    float* __restrict__ out) {
  int b = threadIdx.x;
  float s0 = scores[b * 3], s1 = scores[b * 3 + 1], s2 = scores[b * 3 + 2];
  float m = fmaxf(s0, fmaxf(s1, s2));
  float lse = m + logf(expf(s0 - m) + expf(s1 - m) + expf(s2 - m));
  int lab = labels[b];
  float sl = lab == 0 ? s0 : (lab == 1 ? s1 : s2);
  float closs = lse - sl;
  float sn = snb[b];
  #pragma unroll
  for (int off = 32; off > 0; off >>= 1) {
    closs += __shfl_down(closs, off);
    sn    += __shfl_down(sn, off);
  }
  if (b == 0) {
    float pena = fmaxf(trans[2] - trans[0], 0.f) + fmaxf(trans[1] - trans[3], 0.f);
    out[0] = closs / 64.f;
    out[1] = pena / 64.f + sn / 64.f;
  }
}

// ---------------------------------------------------------------------------
extern "C" void kernel_launch(void* const* d_in, const int* in_sizes, int n_in,
                              void* d_out, int out_size, void* d_ws, size_t ws_size,
                              hipStream_t stream) {
  const float* sents  = (const float*)d_in[0];
  const int*   masks  = (const int*)d_in[1];
  const int*   lens   = (const int*)d_in[2];
  const int*   labels = (const int*)d_in[3];
  const float* me     = (const float*)d_in[4];
  const float* Wihf   = (const float*)d_in[5];
  const float* Whhf   = (const float*)d_in[6];
  const float* bf     = (const float*)d_in[7];
  const float* Wihb   = (const float*)d_in[8];
  const float* Whhb   = (const float*)d_in[9];
  const float* bb     = (const float*)d_in[10];
  const float* Wtri   = (const float*)d_in[11];
  const float* btri   = (const float*)d_in[12];
  const float* Wlab   = (const float*)d_in[13];
  const float* blab   = (const float*)d_in[14];
  const float* trans  = (const float*)d_in[15];
  float* out = (float*)d_out;

  float*     XW   = (float*)d_ws;                              // 16384*2048 f (128MiB)
  float*     CTX  = XW + (size_t)16384 * 2048;                 // 8388608 f (32MiB)
  _Float16*  PA   = (_Float16*)CTX;                            // overlaps CTX (dead until k_lstm)
  _Float16*  WH   = (_Float16*)(CTX + (size_t)64 * 256 * 512); // 524288 halfs (1MiB)
  float*     PRE  = (float*)(WH + 524288);                     // 4096
  float*     TRI  = PRE + 4096;                                // 32768
  float*     ALPH = TRI + 32768;                               // 32768
  float*     SEL  = ALPH + 32768;                              // 16384
  float*     SCOR = SEL + 16384;                               // 192
  float*     SNB  = SCOR + 192;                                // 64
  _Float16*  PB   = (_Float16*)(SNB + 64);                     // 2097152 halfs (4MiB)

  hipLaunchKernelGGL(k_pre,    dim3(16),       dim3(256),  0, stream, me, Wihf, Wihb, bf, bb, PRE);
  hipLaunchKernelGGL(k_wph,    dim3(256),      dim3(256),  0, stream, Whhf, Whhb, WH);
  hipLaunchKernelGGL(k_pack,   dim3(9216),     dim3(256),  0, stream, sents, Wihf, Wihb, PA, PB);
  hipLaunchKernelGGL(k_mm,     dim3(16, 128),  dim3(256),  0, stream, PA, PB, PRE, masks, XW);
  hipLaunchKernelGGL(k_lstm,   dim3(32),       dim3(1024), 0, stream, XW, WH, lens, CTX);
  hipLaunchKernelGGL(k_avgtri, dim3(64),       dim3(256),  0, stream, CTX, masks, Wtri, btri, TRI);
  hipLaunchKernelGGL(k_crf,    dim3(1),        dim3(64),   0, stream, TRI, lens, trans, ALPH, SEL, SNB);
  hipLaunchKernelGGL(k_sentv,  dim3(64),       dim3(256),  0, stream, CTX, SEL, Wlab, blab, SCOR);
  hipLaunchKernelGGL(k_final,  dim3(1),        dim3(64),   0, stream, SCOR, labels, SNB, trans, out);
}

// Round 4
// 2372.163 us; speedup vs baseline: 1.8665x; 1.0498x over previous
//
#include <hip/hip_runtime.h>
#include <cmath>

#define B_   64
#define T_   256
#define D_   1024
#define DIN_ 1074
#define H_   256

typedef _Float16 h2_t  __attribute__((ext_vector_type(2)));
typedef _Float16 f16x8 __attribute__((ext_vector_type(8)));
typedef float    f32x4 __attribute__((ext_vector_type(4)));

// ---------------------------------------------------------------------------
// PRE[mv][n] = bias_dir[row] + sum_{k<50} mask_embed[mv][k] * W_ih_dir[row][1024+k]
// ---------------------------------------------------------------------------
__global__ __launch_bounds__(256) void k_pre(
    const float* __restrict__ me, const float* __restrict__ Wf,
    const float* __restrict__ Wb, const float* __restrict__ bf,
    const float* __restrict__ bb, float* __restrict__ PRE) {
  int idx = blockIdx.x * 256 + threadIdx.x;   // 4096 total
  if (idx >= 4096) return;
  int mv = idx >> 11, n = idx & 2047;
  int dir = n >> 10, row = n & 1023;
  const float* W    = dir ? Wb : Wf;
  const float* bias = dir ? bb : bf;
  const float* wrow = W + (size_t)row * DIN_ + 1024;
  const float* m    = me + mv * 50;
  float s = bias[row];
  #pragma unroll 10
  for (int k = 0; k < 50; ++k) s += m[k] * wrow[k];
  PRE[idx] = s;
}

// ---------------------------------------------------------------------------
// Pack W_hh (both dirs) to fp16, layout WH[dir][k8][row=gate*256+hc][8 halfs]
// ---------------------------------------------------------------------------
__global__ __launch_bounds__(256) void k_wph(
    const float* __restrict__ Whf, const float* __restrict__ Whb,
    _Float16* __restrict__ WH) {
  int idx = blockIdx.x * 256 + threadIdx.x;   // 65536 total
  int dir = idx >> 15, rem = idx & 32767;
  int k8 = rem >> 10, gate = (rem >> 8) & 3, hc = rem & 255;
  const float* W = dir ? Whb : Whf;
  const float* src = W + (size_t)(gate * 256 + hc) * H_ + k8 * 8;
  _Float16* dst = WH + ((size_t)(((dir * 32 + k8) * 4 + gate) * 256 + hc)) * 8;
  #pragma unroll
  for (int e = 0; e < 8; ++e) dst[e] = (_Float16)src[e];
}

// ---------------------------------------------------------------------------
// Pack sents -> PA fp16 [16384][1024] and W_ih rows (cols 0..1023) -> PB fp16
// ---------------------------------------------------------------------------
__global__ __launch_bounds__(256) void k_pack(
    const float* __restrict__ sents, const float* __restrict__ Wf,
    const float* __restrict__ Wb, _Float16* __restrict__ PA,
    _Float16* __restrict__ PB) {
  int i = blockIdx.x * 256 + threadIdx.x;     // 2359296 total
  if (i < 2097152) {
    size_t off = (size_t)i * 8;
    float4 a = *(const float4*)(sents + off);
    float4 b = *(const float4*)(sents + off + 4);
    _Float16 h[8] = {(_Float16)a.x, (_Float16)a.y, (_Float16)a.z, (_Float16)a.w,
                     (_Float16)b.x, (_Float16)b.y, (_Float16)b.z, (_Float16)b.w};
    *(uint4*)(PA + off) = *(const uint4*)h;
  } else {
    int j = i - 2097152;                      // 262144
    int n = j >> 7, k8 = j & 127;
    const float* src = (n < 1024) ? (Wf + (size_t)n * DIN_ + k8 * 8)
                                  : (Wb + (size_t)(n - 1024) * DIN_ + k8 * 8);
    float2 a0 = *(const float2*)(src);
    float2 a1 = *(const float2*)(src + 2);
    float2 a2 = *(const float2*)(src + 4);
    float2 a3 = *(const float2*)(src + 6);
    _Float16 h[8] = {(_Float16)a0.x, (_Float16)a0.y, (_Float16)a1.x, (_Float16)a1.y,
                     (_Float16)a2.x, (_Float16)a2.y, (_Float16)a3.x, (_Float16)a3.y};
    *(uint4*)(PB + (size_t)n * 1024 + k8 * 8) = *(const uint4*)h;
  }
}

// ---------------------------------------------------------------------------
// XW = PA @ PB^T + PRE[mask] : M=16384, N=2048, K=1024, fp16 MFMA 16x16x32.
// ---------------------------------------------------------------------------
__global__ __launch_bounds__(256) void k_mm(
    const _Float16* __restrict__ PA, const _Float16* __restrict__ PB,
    const float* __restrict__ PRE, const int* __restrict__ masks,
    float* __restrict__ XW) {
  __shared__ __align__(16) _Float16 Al[128 * 32];
  __shared__ __align__(16) _Float16 Bl[128 * 32];
  int tid = threadIdx.x;
  int lane = tid & 63, wave = tid >> 6;
  int wr = wave >> 1, wc = wave & 1;
  int m0 = blockIdx.y * 128, n0 = blockIdx.x * 128;

  int r0 = tid >> 2;
  int kc = (tid & 3) * 8;
  const _Float16* asrc0 = PA + (size_t)(m0 + r0) * 1024 + kc;
  const _Float16* asrc1 = asrc0 + (size_t)64 * 1024;
  const _Float16* bsrc0 = PB + (size_t)(n0 + r0) * 1024 + kc;
  const _Float16* bsrc1 = bsrc0 + (size_t)64 * 1024;
  _Float16* adst0 = Al + r0 * 32 + kc;
  _Float16* adst1 = Al + (r0 + 64) * 32 + kc;
  _Float16* bdst0 = Bl + r0 * 32 + kc;
  _Float16* bdst1 = Bl + (r0 + 64) * 32 + kc;

  f32x4 acc[4][4];
  #pragma unroll
  for (int i = 0; i < 4; ++i)
    #pragma unroll
    for (int j = 0; j < 4; ++j)
      acc[i][j] = (f32x4){0.f, 0.f, 0.f, 0.f};

  int fr = lane & 15, fk = (lane >> 4) * 8;
  const _Float16* arow = Al + (wr * 64 + fr) * 32 + fk;
  const _Float16* brow = Bl + (wc * 64 + fr) * 32 + fk;

  for (int k0 = 0; k0 < 1024; k0 += 32) {
    uint4 a0 = *(const uint4*)(asrc0 + k0);
    uint4 a1 = *(const uint4*)(asrc1 + k0);
    uint4 b0 = *(const uint4*)(bsrc0 + k0);
    uint4 b1 = *(const uint4*)(bsrc1 + k0);
    __syncthreads();
    *(uint4*)adst0 = a0; *(uint4*)adst1 = a1;
    *(uint4*)bdst0 = b0; *(uint4*)bdst1 = b1;
    __syncthreads();
    f16x8 af[4], bf[4];
    #pragma unroll
    for (int fm = 0; fm < 4; ++fm) af[fm] = *(const f16x8*)(arow + fm * 16 * 32);
    #pragma unroll
    for (int fn = 0; fn < 4; ++fn) bf[fn] = *(const f16x8*)(brow + fn * 16 * 32);
    #pragma unroll
    for (int fm = 0; fm < 4; ++fm)
      #pragma unroll
      for (int fn = 0; fn < 4; ++fn)
        acc[fm][fn] = __builtin_amdgcn_mfma_f32_16x16x32_f16(af[fm], bf[fn], acc[fm][fn], 0, 0, 0);
  }

  int cr = (lane >> 4) * 4;
  #pragma unroll
  for (int fm = 0; fm < 4; ++fm) {
    #pragma unroll
    for (int r = 0; r < 4; ++r) {
      int m = m0 + wr * 64 + fm * 16 + cr + r;
      int mv = masks[m];
      const float* pr = PRE + mv * 2048;
      float* orow = XW + (size_t)m * 2048;
      #pragma unroll
      for (int fn = 0; fn < 4; ++fn) {
        int n = n0 + wc * 64 + fn * 16 + fr;
        orow[n] = acc[fm][fn][r] + pr[n];
      }
    }
  }
}

// ---------------------------------------------------------------------------
// Batched persistent LSTM v4: 32 WGs = 16 groups(4 batches) x 2 dirs,
// 512 thr (8 waves). Thread owns rows r0=tid (gate g0=tid>>8 in {0,1}) and
// r1=tid+512 (gate g0+2) for all 4 batches.
// W split: slices 0..7 in LDS (128KB, loaded once), 8..19 register-resident,
// 20..31 streamed per step (192KB). 146KB LDS forces 1 WG/CU -> VGPR cap 256,
// so the compiler has no occupancy reason to rematerialize the W registers.
// ---------------------------------------------------------------------------
#define NLDS 8
#define NRG  12
#define NST  12

#define DOT_SLICE(WA, WB, K8)                                           \
  {                                                                     \
    const unsigned int* wqa_ = (const unsigned int*)&(WA);              \
    const unsigned int* wqb_ = (const unsigned int*)&(WB);              \
    _Pragma("unroll")                                                   \
    for (int q_ = 0; q_ < 4; ++q_) {                                    \
      uint4 hv_ = hp[(K8) * 4 + q_];                                    \
      h2_t wa_ = __builtin_bit_cast(h2_t, wqa_[q_]);                    \
      h2_t wb_ = __builtin_bit_cast(h2_t, wqb_[q_]);                    \
      h2_t hx_ = __builtin_bit_cast(h2_t, hv_.x);                       \
      h2_t hy_ = __builtin_bit_cast(h2_t, hv_.y);                       \
      h2_t hz_ = __builtin_bit_cast(h2_t, hv_.z);                       \
      h2_t hw_ = __builtin_bit_cast(h2_t, hv_.w);                       \
      aA0 = __builtin_amdgcn_fdot2(wa_, hx_, aA0, false);               \
      aA1 = __builtin_amdgcn_fdot2(wa_, hy_, aA1, false);               \
      aA2 = __builtin_amdgcn_fdot2(wa_, hz_, aA2, false);               \
      aA3 = __builtin_amdgcn_fdot2(wa_, hw_, aA3, false);               \
      aB0 = __builtin_amdgcn_fdot2(wb_, hx_, aB0, false);               \
      aB1 = __builtin_amdgcn_fdot2(wb_, hy_, aB1, false);               \
      aB2 = __builtin_amdgcn_fdot2(wb_, hz_, aB2, false);               \
      aB3 = __builtin_amdgcn_fdot2(wb_, hw_, aB3, false);               \
    }                                                                   \
  }

__global__ __launch_bounds__(512, 2) void k_lstm(
    const float* __restrict__ XW, const _Float16* __restrict__ WH,
    const int* __restrict__ lens, float* __restrict__ ctx) {
  int bx = blockIdx.x;
  int dir = bx & 1, grp = bx >> 1;
  int tid = threadIdx.x;
  int hc = tid & 255;
  int g0 = tid >> 8;                 // gate for row A; also batch-pair index j2

  __shared__ __align__(16) uint4    Wl[NLDS * 1024];   // 128 KB
  __shared__ __align__(16) _Float16 hsT[1024];         // 2 KB [k2][j][2]
  __shared__ __align__(16) float    gacc[4 * 1024];    // 16 KB [j][gate][hc]

  int b0 = grp * 4;
  int lenA = lens[b0 + g0];          // pair A: batch j = g0
  int lenB = lens[b0 + g0 + 2];      // pair B: batch j = g0+2
  int l0 = lens[b0], l1 = lens[b0 + 1], l2 = lens[b0 + 2], l3 = lens[b0 + 3];
  int lmax = max(max(l0, l1), max(l2, l3));

  const uint4* WHd = (const uint4*)WH + (size_t)dir * 32768;

  // one-time LDS preload of slices 0..7 (dense, coalesced)
  #pragma unroll
  for (int i = 0; i < 16; ++i) Wl[i * 512 + tid] = WHd[i * 512 + tid];

  // register-resident slices 8..19
  uint4 wrA[NRG], wrB[NRG];
  #pragma unroll
  for (int i = 0; i < NRG; ++i) {
    wrA[i] = WHd[(NLDS + i) * 1024 + tid];
    wrB[i] = WHd[(NLDS + i) * 1024 + tid + 512];
  }

  hsT[tid] = (_Float16)0.f;
  hsT[tid + 512] = (_Float16)0.f;
  float cA = 0.f, cB = 0.f;

  const uint4* hp = (const uint4*)hsT;
  const float* xwA = XW + (size_t)(b0 + g0) * T_ * 2048 + dir * 1024;
  const float* xwB = XW + (size_t)(b0 + g0 + 2) * T_ * 2048 + dir * 1024;
  float* cbA = ctx + (size_t)(b0 + g0) * T_ * 512 + dir * 256;
  float* cbB = ctx + (size_t)(b0 + g0 + 2) * T_ * 512 + dir * 256;
  __syncthreads();

  for (int s = 0; s < lmax; ++s) {
    // streamed W: issue early (h-independent, loop-invariant addresses)
    uint4 stA[NST], stB[NST];
    #pragma unroll
    for (int i = 0; i < NST; ++i) {
      stA[i] = WHd[(NLDS + NRG + i) * 1024 + tid];
      stB[i] = WHd[(NLDS + NRG + i) * 1024 + tid + 512];
    }
    // XW gate prefetch for both pairs (clamped addresses)
    int scA = min(s, lenA - 1), scB = min(s, lenB - 1);
    int txA = dir ? (lenA - 1 - scA) : scA;
    int txB = dir ? (lenB - 1 - scB) : scB;
    const float* gA = xwA + (size_t)txA * 2048;
    const float* gB = xwB + (size_t)txB * 2048;
    float gA0 = gA[hc], gA1 = gA[256 + hc], gA2 = gA[512 + hc], gA3 = gA[768 + hc];
    float gB0 = gB[hc], gB1 = gB[256 + hc], gB2 = gB[512 + hc], gB3 = gB[768 + hc];

    float aA0 = 0.f, aA1 = 0.f, aA2 = 0.f, aA3 = 0.f;
    float aB0 = 0.f, aB1 = 0.f, aB2 = 0.f, aB3 = 0.f;

    // register slices (covers stream latency)
    #pragma unroll
    for (int i = 0; i < NRG; ++i) DOT_SLICE(wrA[i], wrB[i], NLDS + i);
    // LDS slices (dense conflict-free reads)
    #pragma unroll
    for (int i = 0; i < NLDS; ++i) {
      uint4 wa = Wl[i * 1024 + tid];
      uint4 wb = Wl[i * 1024 + tid + 512];
      DOT_SLICE(wa, wb, i);
    }
    // streamed slices
    #pragma unroll
    for (int i = 0; i < NST; ++i) DOT_SLICE(stA[i], stB[i], NLDS + NRG + i);

    // gacc[j][gate][hc]
    gacc[0 * 1024 + g0 * 256 + hc] = aA0;
    gacc[1 * 1024 + g0 * 256 + hc] = aA1;
    gacc[2 * 1024 + g0 * 256 + hc] = aA2;
    gacc[3 * 1024 + g0 * 256 + hc] = aA3;
    gacc[0 * 1024 + (g0 + 2) * 256 + hc] = aB0;
    gacc[1 * 1024 + (g0 + 2) * 256 + hc] = aB1;
    gacc[2 * 1024 + (g0 + 2) * 256 + hc] = aB2;
    gacc[3 * 1024 + (g0 + 2) * 256 + hc] = aB3;
    __syncthreads();

    // update pair A: batch j = g0
    if (s < lenA) {
      float gi = gA0 + gacc[g0 * 1024 + 0   + hc];
      float gf = gA1 + gacc[g0 * 1024 + 256 + hc];
      float gg = gA2 + gacc[g0 * 1024 + 512 + hc];
      float go = gA3 + gacc[g0 * 1024 + 768 + hc];
      float si = 1.f / (1.f + expf(-gi));
      float sf = 1.f / (1.f + expf(-gf));
      float so = 1.f / (1.f + expf(-go));
      float cn = sf * cA + si * tanhf(gg);
      float hn = so * tanhf(cn);
      cA = cn;
      cbA[(size_t)txA * 512 + hc] = hn;
      hsT[(hc >> 1) * 8 + g0 * 2 + (hc & 1)] = (_Float16)hn;
    }
    // update pair B: batch j = g0+2
    if (s < lenB) {
      float gi = gB0 + gacc[(g0 + 2) * 1024 + 0   + hc];
      float gf = gB1 + gacc[(g0 + 2) * 1024 + 256 + hc];
      float gg = gB2 + gacc[(g0 + 2) * 1024 + 512 + hc];
      float go = gB3 + gacc[(g0 + 2) * 1024 + 768 + hc];
      float si = 1.f / (1.f + expf(-gi));
      float sf = 1.f / (1.f + expf(-gf));
      float so = 1.f / (1.f + expf(-go));
      float cn = sf * cB + si * tanhf(gg);
      float hn = so * tanhf(cn);
      cB = cn;
      cbB[(size_t)txB * 512 + hc] = hn;
      hsT[(hc >> 1) * 8 + (g0 + 2) * 2 + (hc & 1)] = (_Float16)hn;
    }
    __syncthreads();
  }
  for (int t = lenA; t < T_; ++t) cbA[(size_t)t * 512 + hc] = 0.f;
  for (int t = lenB; t < T_; ++t) cbB[(size_t)t * 512 + hc] = 0.f;
}

// ---------------------------------------------------------------------------
// Per-b: avg over masked t, then tri[b][t][0..1] = (ctx+avg).W_tri^T + b_tri
// ---------------------------------------------------------------------------
__global__ __launch_bounds__(256) void k_avgtri(
    const float* __restrict__ ctx, const int* __restrict__ masks,
    const float* __restrict__ Wtri, const float* __restrict__ btri,
    float* __restrict__ tri) {
  int b = blockIdx.x, tid = threadIdx.x;
  __shared__ float av[512];
  __shared__ float wt[1024];
  wt[tid] = Wtri[tid];             wt[tid + 256] = Wtri[tid + 256];
  wt[tid + 512] = Wtri[tid + 512]; wt[tid + 768] = Wtri[tid + 768];
  const float* cb = ctx + (size_t)b * T_ * 512;
  float s0 = 0.f, s1 = 0.f, msum = 0.f;
  for (int t = 0; t < T_; ++t) {
    int m = masks[b * T_ + t];
    if (m) {
      float mf = (float)m;
      s0 += mf * cb[(size_t)t * 512 + tid];
      s1 += mf * cb[(size_t)t * 512 + 256 + tid];
      msum += mf;
    }
  }
  av[tid] = s0 / msum;
  av[256 + tid] = s1 / msum;
  __syncthreads();
  int wave = tid >> 6, lane = tid & 63;
  float bt0 = btri[0], bt1 = btri[1];
  for (int t = wave; t < T_; t += 4) {
    const float* cr = cb + (size_t)t * 512;
    float p0 = 0.f, p1 = 0.f;
    #pragma unroll
    for (int q = 0; q < 8; ++q) {
      int h = lane + q * 64;
      float x = cr[h] + av[h];
      p0 += x * wt[h];
      p1 += x * wt[512 + h];
    }
    #pragma unroll
    for (int off = 32; off > 0; off >>= 1) {
      p0 += __shfl_down(p0, off);
      p1 += __shfl_down(p1, off);
    }
    if (lane == 0) {
      tri[((size_t)b * T_ + t) * 2 + 0] = p0 + bt0;
      tri[((size_t)b * T_ + t) * 2 + 1] = p1 + bt1;
    }
  }
}

// ---------------------------------------------------------------------------
__device__ __forceinline__ float lse2(float a, float b) {
  float m = fmaxf(a, b);
  return m + logf(expf(a - m) + expf(b - m));
}

__global__ __launch_bounds__(64) void k_crf(
    const float* __restrict__ tri, const int* __restrict__ lens,
    const float* __restrict__ trans, float* __restrict__ alph,
    float* __restrict__ sel, float* __restrict__ snb) {
  int b = threadIdx.x;
  if (b >= 64) return;
  const float* f = tri + (size_t)b * T_ * 2;
  float* aw = alph + (size_t)b * T_ * 2;
  int L = lens[b];
  float t00 = trans[0], t01 = trans[1], t10 = trans[2], t11 = trans[3];
  float a0 = f[0], a1 = f[1];
  aw[0] = a0; aw[1] = a1;
  for (int t = 1; t < T_; ++t) {
    if (t < L) {
      float c0 = f[2 * t]     + lse2(a0 + t00, a1 + t01);
      float c1 = f[2 * t + 1] + lse2(a0 + t10, a1 + t11);
      a0 = c0; a1 = c1;
    }
    aw[2 * t] = a0; aw[2 * t + 1] = a1;
  }
  float logZ = lse2(aw[2 * (L - 1)], aw[2 * (L - 1) + 1]);
  float b0 = 0.f, b1 = 0.f, sn = 0.f;
  {
    float s = (T_ - 1 < L) ? expf(aw[2 * (T_ - 1) + 1] - logZ) : 0.f;
    sel[b * T_ + T_ - 1] = s; sn += s;
  }
  for (int t = T_ - 2; t >= 0; --t) {
    if (t < L - 1) {
      float e0 = b0 + f[2 * (t + 1)];
      float e1 = b1 + f[2 * (t + 1) + 1];
      float n0 = lse2(e0 + t00, e1 + t10);
      float n1 = lse2(e0 + t01, e1 + t11);
      b0 = n0; b1 = n1;
    } else { b0 = 0.f; b1 = 0.f; }
    float s = (t < L) ? expf(aw[2 * t + 1] + b1 - logZ) : 0.f;
    sel[b * T_ + t] = s; sn += s;
  }
  snb[b] = sn;
}

// ---------------------------------------------------------------------------
__global__ __launch_bounds__(256) void k_sentv(
    const float* __restrict__ ctx, const float* __restrict__ sel,
    const float* __restrict__ Wlab, const float* __restrict__ blab,
    float* __restrict__ scores) {
  int b = blockIdx.x, tid = threadIdx.x;
  __shared__ float ss[T_];
  __shared__ float red[3][4];
  ss[tid] = sel[b * T_ + tid];
  __syncthreads();
  const float* cb = ctx + (size_t)b * T_ * 512;
  float sv0 = 0.f, sv1 = 0.f;
  for (int t = 0; t < T_; ++t) {
    float s = ss[t];
    if (s != 0.f) {
      sv0 += s * cb[(size_t)t * 512 + tid];
      sv1 += s * cb[(size_t)t * 512 + 256 + tid];
    }
  }
  int wave = tid >> 6, lane = tid & 63;
  #pragma unroll
  for (int k = 0; k < 3; ++k) {
    float p = sv0 * Wlab[k * 512 + tid] + sv1 * Wlab[k * 512 + 256 + tid];
    #pragma unroll
    for (int off = 32; off > 0; off >>= 1) p += __shfl_down(p, off);
    if (lane == 0) red[k][wave] = p;
  }
  __syncthreads();
  if (tid < 3) {
    float r = red[tid][0] + red[tid][1] + red[tid][2] + red[tid][3];
    scores[b * 3 + tid] = r + blab[tid];
  }
}

// ---------------------------------------------------------------------------
__global__ __launch_bounds__(64) void k_final(
    const float* __restrict__ scores, const int* __restrict__ labels,
    const float* __restrict__ snb, const float* __restrict__ trans,
    float* __restrict__ out) {
  int b = threadIdx.x;
  float s0 = scores[b * 3], s1 = scores[b * 3 + 1], s2 = scores[b * 3 + 2];
  float m = fmaxf(s0, fmaxf(s1, s2));
  float lse = m + logf(expf(s0 - m) + expf(s1 - m) + expf(s2 - m));
  int lab = labels[b];
  float sl = lab == 0 ? s0 : (lab == 1 ? s1 : s2);
  float closs = lse - sl;
  float sn = snb[b];
  #pragma unroll
  for (int off = 32; off > 0; off >>= 1) {
    closs += __shfl_down(closs, off);
    sn    += __shfl_down(sn, off);
  }
  if (b == 0) {
    float pena = fmaxf(trans[2] - trans[0], 0.f) + fmaxf(trans[1] - trans[3], 0.f);
    out[0] = closs / 64.f;
    out[1] = pena / 64.f + sn / 64.f;
  }
}

// ---------------------------------------------------------------------------
extern "C" void kernel_launch(void* const* d_in, const int* in_sizes, int n_in,
                              void* d_out, int out_size, void* d_ws, size_t ws_size,
                              hipStream_t stream) {
  const float* sents  = (const float*)d_in[0];
  const int*   masks  = (const int*)d_in[1];
  const int*   lens   = (const int*)d_in[2];
  const int*   labels = (const int*)d_in[3];
  const float* me     = (const float*)d_in[4];
  const float* Wihf   = (const float*)d_in[5];
  const float* Whhf   = (const float*)d_in[6];
  const float* bf     = (const float*)d_in[7];
  const float* Wihb   = (const float*)d_in[8];
  const float* Whhb   = (const float*)d_in[9];
  const float* bb     = (const float*)d_in[10];
  const float* Wtri   = (const float*)d_in[11];
  const float* btri   = (const float*)d_in[12];
  const float* Wlab   = (const float*)d_in[13];
  const float* blab   = (const float*)d_in[14];
  const float* trans  = (const float*)d_in[15];
  float* out = (float*)d_out;

  float*     XW   = (float*)d_ws;                              // 16384*2048 f (128MiB)
  float*     CTX  = XW + (size_t)16384 * 2048;                 // 8388608 f (32MiB)
  _Float16*  PA   = (_Float16*)CTX;                            // overlaps CTX (dead until k_lstm)
  _Float16*  WH   = (_Float16*)(CTX + (size_t)64 * 256 * 512); // 524288 halfs (1MiB)
  float*     PRE  = (float*)(WH + 524288);                     // 4096
  float*     TRI  = PRE + 4096;                                // 32768
  float*     ALPH = TRI + 32768;                               // 32768
  float*     SEL  = ALPH + 32768;                              // 16384
  float*     SCOR = SEL + 16384;                               // 192
  float*     SNB  = SCOR + 192;                                // 64
  _Float16*  PB   = (_Float16*)(SNB + 64);                     // 2097152 halfs (4MiB)

  hipLaunchKernelGGL(k_pre,    dim3(16),       dim3(256), 0, stream, me, Wihf, Wihb, bf, bb, PRE);
  hipLaunchKernelGGL(k_wph,    dim3(256),      dim3(256), 0, stream, Whhf, Whhb, WH);
  hipLaunchKernelGGL(k_pack,   dim3(9216),     dim3(256), 0, stream, sents, Wihf, Wihb, PA, PB);
  hipLaunchKernelGGL(k_mm,     dim3(16, 128),  dim3(256), 0, stream, PA, PB, PRE, masks, XW);
  hipLaunchKernelGGL(k_lstm,   dim3(32),       dim3(512), 0, stream, XW, WH, lens, CTX);
  hipLaunchKernelGGL(k_avgtri, dim3(64),       dim3(256), 0, stream, CTX, masks, Wtri, btri, TRI);
  hipLaunchKernelGGL(k_crf,    dim3(1),        dim3(64),  0, stream, TRI, lens, trans, ALPH, SEL, SNB);
  hipLaunchKernelGGL(k_sentv,  dim3(64),       dim3(256), 0, stream, CTX, SEL, Wlab, blab, SCOR);
  hipLaunchKernelGGL(k_final,  dim3(1),        dim3(64),  0, stream, SCOR, labels, SNB, trans, out);
}